// Round 11
// baseline (372.501 us; speedup 1.0000x reference)
//
#include <hip/hip_runtime.h>

typedef unsigned short ushort_t;
typedef short bf16x8 __attribute__((ext_vector_type(8)));
typedef float f32x4 __attribute__((ext_vector_type(4)));

#define D_MODEL 2048
#define T_SEQ 2048
#define NB 2
#define NH 16
#define HD 128
#define M_ROWS 4096

__device__ __forceinline__ float b2f(unsigned short u) {
    return __uint_as_float(((unsigned)u) << 16);
}
__device__ __forceinline__ unsigned short f2b(float f) {
    unsigned u = __float_as_uint(f);
    u += 0x7fffu + ((u >> 16) & 1u);
    return (unsigned short)(u >> 16);
}

// async global->LDS, 16B per lane. lds base must be wave-uniform.
__device__ __forceinline__ void g2l16(const ushort_t* g, ushort_t* l) {
    __builtin_amdgcn_global_load_lds(
        (const __attribute__((address_space(1))) unsigned int*)g,
        (__attribute__((address_space(3))) unsigned int*)l, 16, 0, 0);
}

// ---------------------------------------------------------------------------
// Input dtype probe (1 = fp32 inputs). FALLBACK ONLY: host decides dtype from
// in_sizes[0]; this kernel launches only if the convention is unexpected.
// ---------------------------------------------------------------------------
__global__ void detect_dtype(const ushort_t* __restrict__ x, int* __restrict__ flag) {
    __shared__ int cnt;
    if (threadIdx.x == 0) cnt = 0;
    __syncthreads();
    int c = 0;
    for (int i = threadIdx.x; i < 8192; i += 256) {
        int e = (x[i] >> 7) & 0xFF;
        if (e >= 0xC8) ++c;
    }
    atomicAdd(&cnt, c);
    __syncthreads();
    if (threadIdx.x == 0) *flag = (cnt > 16) ? 1 : 0;
}

// ---------------------------------------------------------------------------
// One fused elementwise pass = {x,Wq,Wk,Wv,Wo} conversion + RoPE table.
// ---------------------------------------------------------------------------
#define NCONVB 12288   // (TEN + 4*WEL) / 2048
#define NROPEB 512     // (T_SEQ * 64) / 256

__global__ void convert_rope(const void* __restrict__ s0, const void* __restrict__ s1,
                             const void* __restrict__ s2, const void* __restrict__ s3,
                             const void* __restrict__ s4, ushort_t* __restrict__ dst,
                             float* __restrict__ rtab,
                             int hostfl, const int* __restrict__ flag) {
    const int bx = blockIdx.x;
    if (bx >= NCONVB) {
        int tid = (bx - NCONVB) * 256 + threadIdx.x;   // t*64 + i
        int i = tid & 63, t = tid >> 6;
        float ang = (float)t * exp2f(-(float)i * 0.20762050593046015f);
        rtab[t * 128 + i]      = cosf(ang);
        rtab[t * 128 + 64 + i] = sinf(ang);
        return;
    }
    const size_t TENc = (size_t)M_ROWS * D_MODEL;   // 2^23
    const size_t WELc = (size_t)D_MODEL * D_MODEL;  // 2^22
    size_t i = ((size_t)bx * 256 + threadIdx.x) * 8;
    const void* src;
    size_t off;
    if (i < TENc) {
        src = s0; off = i;
    } else {
        size_t j = i - TENc;
        int wsel = (int)(j >> 22);
        src = (wsel == 0) ? s1 : (wsel == 1) ? s2 : (wsel == 2) ? s3 : s4;
        off = j & (WELc - 1);
    }
    const int fl = (hostfl >= 0) ? hostfl : *flag;
    if (fl) {
        const float* s = (const float*)src + off;
        union { ushort_t u[8]; float4 f; } pk;
        #pragma unroll
        for (int j2 = 0; j2 < 8; ++j2) pk.u[j2] = f2b(s[j2]);
        *(float4*)(dst + i) = pk.f;
    } else {
        *(float4*)(dst + i) = *(const float4*)((const ushort_t*)src + off);
    }
}

// ---------------------------------------------------------------------------
// R11 GEMM body: block tile 256x128 (UNCHANGED -> grid fit preserved), but
// 4 waves (256 threads) x per-wave 128x64 tile (wave grid 2M x 2N).
// Why: R7-R10 showed ~40% MfmaUtil at 8-wave 64x64/wave across 4 schedule
// variants -> geometry-bound, not schedule-bound. Per block per K-step:
//   old: LDS 64KB (~770cy @85B/cy) vs MFMA 516cy  -> LDS-read-bound (67% cap)
//   new: 12 reads/wave feed 32 MFMA -> 48KB (~565cy) vs 516cy -> balanced
// Pipeline identical to R10 (3 buffers, counted vmcnt, 1 barrier/step);
// stage = 6 g2l16/thread (A:4, W:2), 2 stages in flight -> vmcnt(6).
// Swizzle algebra unchanged: store chunk cl^((lr>>1)&3), read quad^((l16>>1)&3).
// mode 0: bf16 store (or fp32 if outf && fl); 1: fused RoPE; 2: Vt.
// ---------------------------------------------------------------------------
#define ABUF4 (256 * 32)          // 8192 elems (16 KB)
#define WBUF4 (128 * 32)          // 4096 elems (8 KB)
#define PBUF4 (ABUF4 + WBUF4)     // 12288 elems = 24 KB per buffer

__device__ __forceinline__ void gemm4_body(const ushort_t* __restrict__ A,
                                           const ushort_t* __restrict__ W,
                                           ushort_t* __restrict__ C,
                                           float* __restrict__ outf,
                                           int fl,
                                           const float* __restrict__ rtab,
                                           int mode, int Ndim,
                                           long bm, long bn,
                                           ushort_t* smem) {
    const int tid  = threadIdx.x;
    const int lane = tid & 63;
    const int w    = tid >> 6;             // 0..3
    const int wrg  = w >> 1;               // 0..1 : 128-row half
    const int wcg  = w & 1;                // 0..1 : 64-col half
    const int quad = lane >> 4, l16 = lane & 15;

    f32x4 acc[8][4];
    #pragma unroll
    for (int i = 0; i < 8; ++i)
        #pragma unroll
        for (int j = 0; j < 4; ++j) acc[i][j] = {0.f, 0.f, 0.f, 0.f};

    // staging thread mapping: per K-step each thread issues 4 A + 2 W loads
    // of 16B; one wave-instruction covers 16 rows (1KB).
    const int lr = lane >> 2;              // row within 16-row group
    const int cl = lane & 3;               // 16B chunk within 64B row
    const int csw = cl ^ ((lr >> 1) & 3);  // pre-swizzled source chunk
    const ushort_t* gA = A + (bm + w * 64 + lr) * D_MODEL + csw * 8;
    const ushort_t* gW = W + (bn + w * 32 + lr) * D_MODEL + csw * 8;

    const int fsl = (l16 >> 1) & 3;        // read-side swizzle

    auto stage = [&](int s, int sb) {
        ushort_t* As = smem + sb * PBUF4;
        ushort_t* Ws = As + ABUF4;
        const int ko = s * 32;
        #pragma unroll
        for (int i = 0; i < 4; ++i)
            g2l16(gA + i * 16 * D_MODEL + ko, As + (w * 4 + i) * 512);
        #pragma unroll
        for (int i = 0; i < 2; ++i)
            g2l16(gW + i * 16 * D_MODEL + ko, Ws + (w * 2 + i) * 512);
    };

    auto kstep = [&](int s, int rb, int vm, bool do_stage) {
        if (vm == 6) asm volatile("s_waitcnt vmcnt(6)" ::: "memory");
        else         asm volatile("s_waitcnt vmcnt(0)" ::: "memory");
        __builtin_amdgcn_sched_barrier(0);
        __builtin_amdgcn_s_barrier();
        __builtin_amdgcn_sched_barrier(0);
        if (do_stage) stage(s + 2, (rb + 2) % 3);   // rb literal -> folds
        const ushort_t* As = smem + rb * PBUF4;
        const ushort_t* Ws = As + ABUF4;
        bf16x8 af[8], bf[4];
        #pragma unroll
        for (int i = 0; i < 8; ++i)
            af[i] = *(const bf16x8*)(As + (wrg * 128 + i * 16 + l16) * 32 + (quad ^ fsl) * 8);
        #pragma unroll
        for (int j = 0; j < 4; ++j)
            bf[j] = *(const bf16x8*)(Ws + (wcg * 64 + j * 16 + l16) * 32 + (quad ^ fsl) * 8);
        __builtin_amdgcn_s_setprio(1);
        #pragma unroll
        for (int i = 0; i < 8; ++i)
            #pragma unroll
            for (int j = 0; j < 4; ++j)
                acc[i][j] = __builtin_amdgcn_mfma_f32_16x16x32_bf16(af[i], bf[j], acc[i][j], 0, 0, 0);
        __builtin_amdgcn_s_setprio(0);
    };

    stage(0, 0); stage(1, 1);              // 12 loads in flight
    for (int s = 0; s < 60; s += 3) {      // steps 0..59, stages 2..61
        kstep(s + 0, 0, 6, true);
        kstep(s + 1, 1, 6, true);
        kstep(s + 2, 2, 6, true);
    }
    kstep(60, 0, 6, true);                 // stages 62 -> buf 2
    kstep(61, 1, 6, true);                 // stages 63 -> buf 0
    kstep(62, 2, 6, false);
    kstep(63, 0, 0, false);
    __syncthreads();   // all LDS reads retired before epilogue reuses smem

    if (mode == 2) {
        // Vt epilogue: transposed image [128 d][256 t] in LDS, store along t.
        #pragma unroll
        for (int i = 0; i < 8; ++i)
            #pragma unroll
            for (int j = 0; j < 4; ++j)
                #pragma unroll
                for (int r = 0; r < 4; ++r) {
                    int row = wrg * 128 + i * 16 + quad * 4 + r;  // t in tile [0,256)
                    int col = wcg * 64 + j * 16 + l16;            // d in head [0,128)
                    smem[col * 256 + ((((row >> 3) ^ (col & 7)) << 3) | (row & 7))] =
                        f2b(acc[i][j][r]);
                }
        __syncthreads();
        const int b = (int)(bm >> 11), t0 = (int)(bm & 2047), h = (int)(bn >> 7);
        const size_t obase = ((size_t)(b * NH + h) * HD) * T_SEQ;
        #pragma unroll
        for (int it = 0; it < 16; ++it) {
            int dd  = it * 8 + (tid >> 5);      // [0,128)
            int tch = tid & 31;                 // [0,32): 256 t / 8
            bf16x8 v = *(const bf16x8*)(smem + dd * 256 + ((tch ^ (dd & 7)) << 3));
            *(bf16x8*)(C + obase + (size_t)dd * T_SEQ + t0 + tch * 8) = v;
        }
        return;
    }

    const int as_f32 = (outf != nullptr) && (fl != 0);
    if (!as_f32) {
        // scatter full 256x128 bf16 image (64 KB)
        #pragma unroll
        for (int i = 0; i < 8; ++i)
            #pragma unroll
            for (int j = 0; j < 4; ++j)
                #pragma unroll
                for (int r = 0; r < 4; ++r) {
                    int row = wrg * 128 + i * 16 + quad * 4 + r;
                    int col = wcg * 64 + j * 16 + l16;
                    int ch = col >> 3, off = col & 7;
                    smem[row * 128 + (((ch ^ (row & 7)) << 3) | off)] = f2b(acc[i][j][r]);
                }
        __syncthreads();
        if (mode == 1) {
            #pragma unroll
            for (int it = 0; it < 16; ++it) {
                int row = it * 16 + (tid >> 4);   // [0,256)
                int ch  = tid & 15;
                int t = (int)((bm + row) & 2047);
                bf16x8 v = *(const bf16x8*)(smem + row * 128 + ((ch ^ (row & 7)) << 3));
                bf16x8 p = *(const bf16x8*)(smem + row * 128 + (((ch ^ 8) ^ (row & 7)) << 3));
                const float* cr = rtab + t * 128 + (ch & 7) * 8;
                float sgn = (ch < 8) ? -1.f : 1.f;
                union { ushort_t u[8]; float4 f[1]; } o;
                #pragma unroll
                for (int j = 0; j < 8; ++j) {
                    float cv = cr[j], sv = cr[64 + j];
                    o.u[j] = f2b(b2f(((const ushort_t*)&v)[j]) * cv +
                                 sgn * b2f(((const ushort_t*)&p)[j]) * sv);
                }
                *(bf16x8*)(C + (bm + row) * Ndim + bn + ch * 8) = *(const bf16x8*)o.u;
            }
        } else {
            #pragma unroll
            for (int it = 0; it < 16; ++it) {
                int row = it * 16 + (tid >> 4);
                int ch  = tid & 15;
                bf16x8 v = *(const bf16x8*)(smem + row * 128 + ((ch ^ (row & 7)) << 3));
                *(bf16x8*)(C + (bm + row) * Ndim + bn + ch * 8) = v;
            }
        }
    } else {
        // fp32 epilogue: two 128-row halves through 64 KB LDS
        float* Fs = (float*)smem;
        #pragma unroll
        for (int half = 0; half < 2; ++half) {
            __syncthreads();
            if (wrg == half) {
                #pragma unroll
                for (int i = 0; i < 8; ++i)
                    #pragma unroll
                    for (int j = 0; j < 4; ++j)
                        #pragma unroll
                        for (int r = 0; r < 4; ++r) {
                            int lrow = i * 16 + quad * 4 + r;          // [0,128)
                            int col = wcg * 64 + j * 16 + l16;
                            int ch = col >> 2, off = col & 3;
                            Fs[lrow * 128 + (((ch ^ (lrow & 7)) << 2) | off)] = acc[i][j][r];
                        }
            }
            __syncthreads();
            #pragma unroll
            for (int it = 0; it < 16; ++it) {
                int lrow = it * 8 + (tid >> 5);   // [0,128)
                int ch = tid & 31;
                float4 v = *(const float4*)(Fs + lrow * 128 + ((ch ^ (lrow & 7)) << 2));
                *(float4*)(outf + (bm + half * 128 + lrow) * Ndim + bn + ch * 4) = v;
            }
        }
    }
}

// Fused QKV projection — ONE 768-block launch (grid fit unchanged).
__global__ __launch_bounds__(256, 2) void gemm_qkv3(const ushort_t* __restrict__ A,
                                                    const ushort_t* __restrict__ Wq,
                                                    const ushort_t* __restrict__ Wk,
                                                    const ushort_t* __restrict__ Wv,
                                                    ushort_t* __restrict__ Qo,
                                                    ushort_t* __restrict__ Ko,
                                                    ushort_t* __restrict__ Vto,
                                                    const float* __restrict__ rtab) {
    __shared__ ushort_t smem[3 * PBUF4];   // 72 KB
    const int wsel = blockIdx.y >> 4;      // 0:Q 1:K 2:V
    const int ym   = blockIdx.y & 15;
    const ushort_t* W = (wsel == 0) ? Wq : (wsel == 1) ? Wk : Wv;
    ushort_t* C       = (wsel == 0) ? Qo : (wsel == 1) ? Ko : Vto;
    const int mode = (wsel == 2) ? 2 : 1;
    // same per-group swizzle as a solo launch
    const int wg  = ym * 16 + blockIdx.x;
    const int swz = (wg & 7) * 32 + (wg >> 3);
    const long bm = (long)(swz >> 4) * 256;
    const long bn = (long)(swz & 15) * 128;
    gemm4_body(A, W, C, nullptr, 0, rtab, mode, D_MODEL, bm, bn, smem);
}

// Final output projection (may need fp32 epilogue). hostfl >= 0: host-known
// dtype; -1: read *flag (fallback path).
__global__ __launch_bounds__(256, 2) void gemm_nt3(const ushort_t* __restrict__ A,
                                                   const ushort_t* __restrict__ W,
                                                   ushort_t* __restrict__ C,
                                                   float* __restrict__ outf,
                                                   int hostfl,
                                                   const int* __restrict__ flag,
                                                   const float* __restrict__ rtab,
                                                   int mode, int Ndim) {
    __shared__ ushort_t smem[3 * PBUF4];   // 72 KB
    const int wg  = blockIdx.y * 16 + blockIdx.x;
    const int swz = (wg & 7) * 32 + (wg >> 3);
    const long bm = (long)(swz >> 4) * 256;
    const long bn = (long)(swz & 15) * 128;
    // Resolve fl and retire any flag read before the pipeline so the loop's
    // vmcnt counting stays exact.
    int fl = (hostfl >= 0) ? hostfl : *flag;
    asm volatile("" :: "v"(fl));
    asm volatile("s_waitcnt vmcnt(0)" ::: "memory");
    gemm4_body(A, W, C, outf, fl, rtab, mode, Ndim, bm, bn, smem);
}

// ---------------------------------------------------------------------------
// Causal flash attention — R3 structure + R6 CU-draw balancing (84.9 us).
// Blocks round-robin to CUs as {c, c+256, c+512, c+768}; remap g=bx>>5 -> qb
// so each CU draw sums to a constant 62 iters:
//   g in [0,8): 31-g | [8,16): g-8 | [16,24): 39-g | [24,32): g-16
// R4 lesson kept: 1024 blocks, 4/CU, 64 VGPR — do not trade TLP for
// per-block work.
// ---------------------------------------------------------------------------
#define NQT (T_SEQ / 64)
#define C2SM 0.1275174452f   // 128^-0.5 * log2(e)
#define MFIX 96.0f

__global__ __launch_bounds__(256, 4) void attn_kernel(const ushort_t* __restrict__ Q,
                                                      const ushort_t* __restrict__ K,
                                                      const ushort_t* __restrict__ Vt,
                                                      ushort_t* __restrict__ O) {
    __shared__ ushort_t Ks[64 * 128];
    __shared__ ushort_t Vs[128 * 64];
    __shared__ ushort_t Ps[4 * 16 * 64];

    const int tid = threadIdx.x;
    const int lane = tid & 63, w = tid >> 6;
    const int quad = lane >> 4, l16 = lane & 15;
    const int bx = blockIdx.x;
    const int g = bx >> 5;
    int qb;
    if (g < 8)       qb = 31 - g;
    else if (g < 16) qb = g - 8;
    else if (g < 24) qb = 39 - g;
    else             qb = g - 16;
    const int bh = bx & 31;
    const int h = bh & 15, b = bh >> 4;

    const size_t qkbase = ((size_t)(b * T_SEQ)) * D_MODEL + h * HD;
    const size_t vtbase = ((size_t)((b * NH + h) * HD)) * T_SEQ;
    const int ck0 = w * 256 + lane;
    ushort_t* Pw = Ps + w * 1024;

    auto stage_K = [&](int kvb) {
        #pragma unroll
        for (int i = 0; i < 4; ++i) {
            int ck = ck0 + i * 64;
            int r = ck >> 4, gg = (ck & 15) ^ (r & 15);
            g2l16(K + qkbase + (size_t)(kvb * 64 + r) * D_MODEL + gg * 8,
                  (ushort_t*)Ks + (size_t)(w * 256 + i * 64) * 8);
        }
    };
    auto stage_V = [&](int kvb) {
        #pragma unroll
        for (int i = 0; i < 4; ++i) {
            int ck = ck0 + i * 64;
            int r = ck >> 3, gg = (ck & 7) ^ (r & 7);
            g2l16(Vt + vtbase + (size_t)r * T_SEQ + kvb * 64 + gg * 8,
                  (ushort_t*)Vs + (size_t)(w * 256 + i * 64) * 8);
        }
    };

    bf16x8 qf[4];
    {
        const ushort_t* qrow = Q + qkbase + (size_t)(qb * 64 + w * 16 + l16) * D_MODEL;
        #pragma unroll
        for (int ks = 0; ks < 4; ++ks)
            qf[ks] = *(const bf16x8*)(qrow + ks * 32 + quad * 8);
    }

    float l_i[4] = {0.f, 0.f, 0.f, 0.f};   // lane-partial; reduced at end
    f32x4 accO[8];
    for (int i = 0; i < 8; ++i) accO[i] = {0.f, 0.f, 0.f, 0.f};

    stage_K(0);                              // prologue

    for (int kvb = 0; kvb <= qb; ++kvb) {
        __syncthreads();                     // K(kvb) landed; Vs free
        stage_V(kvb);                        // in flight during QK^T+softmax

        f32x4 accS[4];
        for (int i = 0; i < 4; ++i) accS[i] = {0.f, 0.f, 0.f, 0.f};
        __builtin_amdgcn_s_setprio(1);
        #pragma unroll
        for (int ks = 0; ks < 4; ++ks) {
            #pragma unroll
            for (int ct = 0; ct < 4; ++ct) {
                bf16x8 bb = *(const bf16x8*)(Ks + (ct * 16 + l16) * 128 +
                                             (((ks * 4 + quad) ^ l16) * 8));
                accS[ct] = __builtin_amdgcn_mfma_f32_16x16x32_bf16(qf[ks], bb, accS[ct], 0, 0, 0);
            }
        }
        __builtin_amdgcn_s_setprio(0);

        if (kvb == qb) {   // diagonal: causal mask
            int qloc = w * 16 + quad * 4;
            for (int ct = 0; ct < 4; ++ct) {
                int key = ct * 16 + l16;
                for (int r = 0; r < 4; ++r)
                    if (key > qloc + r) accS[ct][r] = -1e30f;
            }
        }

        // p = exp2((s - M) * c); accumulate lane-partial l; store P to LDS
        #pragma unroll
        for (int ct = 0; ct < 4; ++ct) {
            #pragma unroll
            for (int r = 0; r < 4; ++r) {
                float pv = exp2f((accS[ct][r] - MFIX) * C2SM);
                l_i[r] += pv;
                int col = ct * 16 + l16;
                int row = quad * 4 + r;
                Pw[row * 64 + ((((col >> 3) ^ (row & 7)) << 3) | (col & 7))] = f2b(pv);
            }
        }

        __syncthreads();                     // V(kvb) landed; Ks free
        if (kvb < qb) stage_K(kvb + 1);      // in flight during PV

        __builtin_amdgcn_s_setprio(1);
        #pragma unroll
        for (int kk2 = 0; kk2 < 2; ++kk2) {
            bf16x8 a = *(const bf16x8*)(Pw + l16 * 64 + (((kk2 * 4 + quad) ^ (l16 & 7)) << 3));
            #pragma unroll
            for (int ct = 0; ct < 8; ++ct) {
                bf16x8 bb = *(const bf16x8*)(Vs + (ct * 16 + l16) * 64 +
                                             (((kk2 * 4 + quad) ^ (l16 & 7)) * 8));
                accO[ct] = __builtin_amdgcn_mfma_f32_16x16x32_bf16(a, bb, accO[ct], 0, 0, 0);
            }
        }
        __builtin_amdgcn_s_setprio(0);
    }

    // end-of-loop l reduction across the 16 lanes of each quad group
    #pragma unroll
    for (int r = 0; r < 4; ++r) {
        for (int off = 1; off < 16; off <<= 1)
            l_i[r] += __shfl_xor(l_i[r], off);
        l_i[r] = 1.f / l_i[r];
    }

    for (int ct = 0; ct < 8; ++ct)
        for (int r = 0; r < 4; ++r) {
            size_t row = (size_t)(b * T_SEQ + qb * 64 + w * 16 + quad * 4 + r);
            O[row * D_MODEL + h * HD + ct * 16 + l16] = f2b(accO[ct][r] * l_i[r]);
        }
}

// ---------------------------------------------------------------------------
extern "C" void kernel_launch(void* const* d_in, const int* in_sizes, int n_in,
                              void* d_out, int out_size, void* d_ws, size_t ws_size,
                              hipStream_t stream) {
    const size_t TEN = (size_t)M_ROWS * D_MODEL;
    const size_t WEL = (size_t)D_MODEL * D_MODEL;

    char* ws = (char*)d_ws;
    int* flag = (int*)ws;
    ushort_t* xb  = (ushort_t*)(ws + 256);
    ushort_t* Wqb = xb  + TEN;
    ushort_t* Wkb = Wqb + WEL;
    ushort_t* Wvb = Wkb + WEL;
    ushort_t* Wob = Wvb + WEL;
    ushort_t* Qb  = Wob + WEL;
    ushort_t* Kb  = Qb + TEN;
    ushort_t* attn = Kb + TEN;
    ushort_t* Vt  = attn + TEN;
    float* rtab = (float*)(Vt + TEN); // 2048*128 floats = 1 MB

    // Host-side dtype decision from in_sizes[0] (bytes). Fallback to the GPU
    // probe only if the convention is unexpected.
    int hostfl = -1;
    if (in_sizes && n_in > 0) {
        if (in_sizes[0] == (int)(TEN * 4)) hostfl = 1;        // fp32
        else if (in_sizes[0] == (int)(TEN * 2)) hostfl = 0;   // bf16
    }
    if (hostfl < 0)
        detect_dtype<<<1, 256, 0, stream>>>((const ushort_t*)d_in[0], flag);

    convert_rope<<<NCONVB + NROPEB, 256, 0, stream>>>(
        d_in[0], d_in[1], d_in[2], d_in[3], d_in[4], xb, rtab, hostfl, flag);

    // Fused QKV: one 768-block launch.
    gemm_qkv3<<<dim3(16, 48), 256, 0, stream>>>(xb, Wqb, Wkb, Wvb, Qb, Kb, Vt, rtab);

    attn_kernel<<<dim3(NQT * NB * NH), 256, 0, stream>>>(Qb, Kb, Vt, attn);

    gemm_nt3<<<dim3(16, 16), 256, 0, stream>>>(attn, Wob, (ushort_t*)d_out,
                                               (float*)d_out, hostfl, flag, rtab,
                                               0, D_MODEL);
}

// Round 12
// 371.772 us; speedup vs baseline: 1.0020x; 1.0020x over previous
//
#include <hip/hip_runtime.h>

typedef unsigned short ushort_t;
typedef short bf16x8 __attribute__((ext_vector_type(8)));
typedef float f32x4 __attribute__((ext_vector_type(4)));

#define D_MODEL 2048
#define T_SEQ 2048
#define NB 2
#define NH 16
#define HD 128
#define M_ROWS 4096

__device__ __forceinline__ float b2f(unsigned short u) {
    return __uint_as_float(((unsigned)u) << 16);
}
__device__ __forceinline__ unsigned short f2b(float f) {
    unsigned u = __float_as_uint(f);
    u += 0x7fffu + ((u >> 16) & 1u);
    return (unsigned short)(u >> 16);
}

// async global->LDS, 16B per lane. lds base must be wave-uniform.
__device__ __forceinline__ void g2l16(const ushort_t* g, ushort_t* l) {
    __builtin_amdgcn_global_load_lds(
        (const __attribute__((address_space(1))) unsigned int*)g,
        (__attribute__((address_space(3))) unsigned int*)l, 16, 0, 0);
}

// ---------------------------------------------------------------------------
// Input dtype probe (1 = fp32 inputs). FALLBACK ONLY: host decides dtype from
// in_sizes[0]; this kernel launches only if the convention is unexpected.
// ---------------------------------------------------------------------------
__global__ void detect_dtype(const ushort_t* __restrict__ x, int* __restrict__ flag) {
    __shared__ int cnt;
    if (threadIdx.x == 0) cnt = 0;
    __syncthreads();
    int c = 0;
    for (int i = threadIdx.x; i < 8192; i += 256) {
        int e = (x[i] >> 7) & 0xFF;
        if (e >= 0xC8) ++c;
    }
    atomicAdd(&cnt, c);
    __syncthreads();
    if (threadIdx.x == 0) *flag = (cnt > 16) ? 1 : 0;
}

// ---------------------------------------------------------------------------
// One fused elementwise pass = {x,Wq,Wk,Wv,Wo} conversion + RoPE table.
// ---------------------------------------------------------------------------
#define NCONVB 12288   // (TEN + 4*WEL) / 2048
#define NROPEB 512     // (T_SEQ * 64) / 256

__global__ void convert_rope(const void* __restrict__ s0, const void* __restrict__ s1,
                             const void* __restrict__ s2, const void* __restrict__ s3,
                             const void* __restrict__ s4, ushort_t* __restrict__ dst,
                             float* __restrict__ rtab,
                             int hostfl, const int* __restrict__ flag) {
    const int bx = blockIdx.x;
    if (bx >= NCONVB) {
        int tid = (bx - NCONVB) * 256 + threadIdx.x;   // t*64 + i
        int i = tid & 63, t = tid >> 6;
        float ang = (float)t * exp2f(-(float)i * 0.20762050593046015f);
        rtab[t * 128 + i]      = cosf(ang);
        rtab[t * 128 + 64 + i] = sinf(ang);
        return;
    }
    const size_t TENc = (size_t)M_ROWS * D_MODEL;   // 2^23
    const size_t WELc = (size_t)D_MODEL * D_MODEL;  // 2^22
    size_t i = ((size_t)bx * 256 + threadIdx.x) * 8;
    const void* src;
    size_t off;
    if (i < TENc) {
        src = s0; off = i;
    } else {
        size_t j = i - TENc;
        int wsel = (int)(j >> 22);
        src = (wsel == 0) ? s1 : (wsel == 1) ? s2 : (wsel == 2) ? s3 : s4;
        off = j & (WELc - 1);
    }
    const int fl = (hostfl >= 0) ? hostfl : *flag;
    if (fl) {
        const float* s = (const float*)src + off;
        union { ushort_t u[8]; float4 f; } pk;
        #pragma unroll
        for (int j2 = 0; j2 < 8; ++j2) pk.u[j2] = f2b(s[j2]);
        *(float4*)(dst + i) = pk.f;
    } else {
        *(float4*)(dst + i) = *(const float4*)((const ushort_t*)src + off);
    }
}

// ---------------------------------------------------------------------------
// R12 GEMM body: 256x128 tile, 512 threads (8 waves, 4Mx2N, per-wave 64x64),
// 4 LDS buffers BK=32 + counted vmcnt (R6 base), NEW: register-fragment
// PING-PONG. R7-R11 post-mortem: all variants with MFMA depending on the
// SAME step's ds_reads pin at ~40% MfmaUtil — LDS latency sits behind the
// barrier on the critical path. Here step s's MFMAs use frags loaded at
// step s-1 (register-only), while step s's ds_reads fill the other set ->
// compiler interleaves MFMA with ds_read; LDS latency hides under MFMA.
//   step s: vmcnt(3)  [stage(s+1) landed; stage(s+2)'s 3 in flight]
//           s_barrier [collective: also orders stage-issue below against
//                      ALL waves' step-(s-1) ds_reads -> no cross-wave WAR]
//           issue stage(s+3) -> buf (s+3)&3
//           ds_read frags(s+1) from buf (s+1)&3 -> other reg set
//           16 MFMA on current reg set
// vmcnt derivation (3 loads/stage, issue after barrier): at step-s vmcnt
// point outstanding = stage(s+1) + stage(s+2) = 6 -> vmcnt(3) waits oldest
// stage(s+1). Tail: s=62 -> vmcnt(0) for stage(63); s=63 no wait.
// Buffers: ds_read(s+1) vs stage(s+3) distinct mod 4; buf (s+3)&3 last read
// at step s-2, two collective barriers before overwrite.
// mode 0: bf16 store (or fp32 if outf && fl); 1: fused RoPE; 2: Vt.
// ---------------------------------------------------------------------------
#define ABUF3 (256 * 32)          // 8192 elems
#define WBUF3 (128 * 32)          // 4096 elems
#define PBUF3 (ABUF3 + WBUF3)     // 12288 elems = 24 KB per buffer

__device__ __forceinline__ void gemm3_body(const ushort_t* __restrict__ A,
                                           const ushort_t* __restrict__ W,
                                           ushort_t* __restrict__ C,
                                           float* __restrict__ outf,
                                           int fl,
                                           const float* __restrict__ rtab,
                                           int mode, int Ndim,
                                           long bm, long bn,
                                           ushort_t* smem) {
    const int tid  = threadIdx.x;
    const int lane = tid & 63;
    const int w    = tid >> 6;             // 0..7
    const int wr   = w >> 1;               // 0..3 : 64-row group
    const int wc   = w & 1;                // 0..1 : 64-col group
    const int quad = lane >> 4, l16 = lane & 15;
    const int Kd   = D_MODEL;

    f32x4 acc[4][4];
    #pragma unroll
    for (int i = 0; i < 4; ++i)
        #pragma unroll
        for (int j = 0; j < 4; ++j) acc[i][j] = {0.f, 0.f, 0.f, 0.f};

    // staging thread mapping: per K-step (32 elems) each thread does
    // 2 A-loads + 1 W-load of 16B. Wave-instruction j covers 16 rows (1KB).
    const int lr = lane >> 2;              // row within 16-row group
    const int cl = lane & 3;               // 16B chunk within 64B row
    const int rowA0 = (w * 2 + 0) * 16 + lr;
    const int rowA1 = (w * 2 + 1) * 16 + lr;
    const int rowW  = w * 16 + lr;
    // pre-swizzled global sources: LDS slot cl holds global chunk cl^f(row)
    const ushort_t* gA0 = A + (bm + rowA0) * Kd + ((cl ^ ((rowA0 >> 1) & 3)) * 8);
    const ushort_t* gA1 = A + (bm + rowA1) * Kd + ((cl ^ ((rowA1 >> 1) & 3)) * 8);
    const ushort_t* gW  = W + (bn + rowW)  * Kd + ((cl ^ ((rowW  >> 1) & 3)) * 8);

    const int fsl = (l16 >> 1) & 3;        // read-side swizzle

    auto stage = [&](int s, int sb) {
        ushort_t* As = smem + sb * PBUF3;
        ushort_t* Ws = As + ABUF3;
        const int ko = s * 32;
        g2l16(gA0 + ko, As + (w * 2 + 0) * 512);
        g2l16(gA1 + ko, As + (w * 2 + 1) * 512);
        g2l16(gW + ko, Ws + w * 512);
    };

    bf16x8 afA[4], bfA[4], afB[4], bfB[4];

    auto ldfrags = [&](int rb, bf16x8 (&af)[4], bf16x8 (&bf)[4]) {
        const ushort_t* As = smem + rb * PBUF3;
        const ushort_t* Ws = As + ABUF3;
        #pragma unroll
        for (int i = 0; i < 4; ++i)
            af[i] = *(const bf16x8*)(As + (wr * 64 + i * 16 + l16) * 32 + (quad ^ fsl) * 8);
        #pragma unroll
        for (int j = 0; j < 4; ++j)
            bf[j] = *(const bf16x8*)(Ws + (wc * 64 + j * 16 + l16) * 32 + (quad ^ fsl) * 8);
    };

    auto domfma = [&](bf16x8 (&af)[4], bf16x8 (&bf)[4]) {
        __builtin_amdgcn_s_setprio(1);
        #pragma unroll
        for (int i = 0; i < 4; ++i)
            #pragma unroll
            for (int j = 0; j < 4; ++j)
                acc[i][j] = __builtin_amdgcn_mfma_f32_16x16x32_bf16(af[i], bf[j], acc[i][j], 0, 0, 0);
        __builtin_amdgcn_s_setprio(0);
    };

    // step: vm = 3 (steady), 0 (drain for last ds_read), -1 (skip wait)
    auto step = [&](int s, int rbn, bf16x8 (&cA)[4], bf16x8 (&cB)[4],
                    bf16x8 (&nA)[4], bf16x8 (&nB)[4], int vm, bool stg, bool ld) {
        if (vm == 3)      asm volatile("s_waitcnt vmcnt(3)" ::: "memory");
        else if (vm == 0) asm volatile("s_waitcnt vmcnt(0)" ::: "memory");
        __builtin_amdgcn_sched_barrier(0);
        __builtin_amdgcn_s_barrier();
        __builtin_amdgcn_sched_barrier(0);
        if (stg) stage(s + 3, (s + 3) & 3);
        if (ld) ldfrags(rbn, nA, nB);
        domfma(cA, cB);
    };

    // prologue: 3 stages in flight (9 loads); wait stage(0); preload frags(0)
    stage(0, 0); stage(1, 1); stage(2, 2);
    asm volatile("s_waitcnt vmcnt(6)" ::: "memory");
    __builtin_amdgcn_sched_barrier(0);
    __builtin_amdgcn_s_barrier();
    __builtin_amdgcn_sched_barrier(0);
    ldfrags(0, afA, bfA);

    for (int s4 = 0; s4 < 60; s4 += 4) {   // steps 0..59, stage 3..62
        step(s4 + 0, (s4 + 1) & 3, afA, bfA, afB, bfB, 3, true, true);
        step(s4 + 1, (s4 + 2) & 3, afB, bfB, afA, bfA, 3, true, true);
        step(s4 + 2, (s4 + 3) & 3, afA, bfA, afB, bfB, 3, true, true);
        step(s4 + 3, (s4 + 4) & 3, afB, bfB, afA, bfA, 3, true, true);
    }
    step(60, 61 & 3, afA, bfA, afB, bfB, 3, true, true);   // stages 63
    step(61, 62 & 3, afB, bfB, afA, bfA, 3, false, true);
    step(62, 63 & 3, afA, bfA, afB, bfB, 0, false, true);  // drain for frags(63)
    step(63, 0,      afB, bfB, afA, bfA, -1, false, false);
    __syncthreads();   // all LDS reads retired before epilogue reuses smem

    if (mode == 2) {
        // Vt epilogue: transposed image [128 d][256 t] in LDS, store along t.
        #pragma unroll
        for (int i = 0; i < 4; ++i)
            #pragma unroll
            for (int j = 0; j < 4; ++j)
                #pragma unroll
                for (int r = 0; r < 4; ++r) {
                    int row = wr * 64 + i * 16 + quad * 4 + r;   // t in tile [0,256)
                    int col = wc * 64 + j * 16 + l16;            // d in head [0,128)
                    smem[col * 256 + ((((row >> 3) ^ (col & 7)) << 3) | (row & 7))] =
                        f2b(acc[i][j][r]);
                }
        __syncthreads();
        const int b = (int)(bm >> 11), t0 = (int)(bm & 2047), h = (int)(bn >> 7);
        const size_t obase = ((size_t)(b * NH + h) * HD) * T_SEQ;
        #pragma unroll
        for (int it = 0; it < 8; ++it) {
            int dd  = it * 16 + (tid >> 5);     // [0,128)
            int tch = tid & 31;                 // [0,32): 256 t / 8
            bf16x8 v = *(const bf16x8*)(smem + dd * 256 + ((tch ^ (dd & 7)) << 3));
            *(bf16x8*)(C + obase + (size_t)dd * T_SEQ + t0 + tch * 8) = v;
        }
        return;
    }

    const int as_f32 = (outf != nullptr) && (fl != 0);
    if (!as_f32) {
        // scatter full 256x128 bf16 image (64 KB)
        #pragma unroll
        for (int i = 0; i < 4; ++i)
            #pragma unroll
            for (int j = 0; j < 4; ++j)
                #pragma unroll
                for (int r = 0; r < 4; ++r) {
                    int row = wr * 64 + i * 16 + quad * 4 + r;
                    int col = wc * 64 + j * 16 + l16;
                    int ch = col >> 3, off = col & 7;
                    smem[row * 128 + (((ch ^ (row & 7)) << 3) | off)] = f2b(acc[i][j][r]);
                }
        __syncthreads();
        if (mode == 1) {
            #pragma unroll
            for (int it = 0; it < 8; ++it) {
                int row = it * 32 + (tid >> 4);   // [0,256)
                int ch  = tid & 15;
                int t = (int)((bm + row) & 2047);
                bf16x8 v = *(const bf16x8*)(smem + row * 128 + ((ch ^ (row & 7)) << 3));
                bf16x8 p = *(const bf16x8*)(smem + row * 128 + (((ch ^ 8) ^ (row & 7)) << 3));
                const float* cr = rtab + t * 128 + (ch & 7) * 8;
                float sgn = (ch < 8) ? -1.f : 1.f;
                union { ushort_t u[8]; float4 f[1]; } o;
                #pragma unroll
                for (int j = 0; j < 8; ++j) {
                    float cv = cr[j], sv = cr[64 + j];
                    o.u[j] = f2b(b2f(((const ushort_t*)&v)[j]) * cv +
                                 sgn * b2f(((const ushort_t*)&p)[j]) * sv);
                }
                *(bf16x8*)(C + (bm + row) * Ndim + bn + ch * 8) = *(const bf16x8*)o.u;
            }
        } else {
            #pragma unroll
            for (int it = 0; it < 8; ++it) {
                int row = it * 32 + (tid >> 4);
                int ch  = tid & 15;
                bf16x8 v = *(const bf16x8*)(smem + row * 128 + ((ch ^ (row & 7)) << 3));
                *(bf16x8*)(C + (bm + row) * Ndim + bn + ch * 8) = v;
            }
        }
    } else {
        // fp32 epilogue: two 128-row halves through 64 KB LDS
        float* Fs = (float*)smem;
        #pragma unroll
        for (int half = 0; half < 2; ++half) {
            __syncthreads();
            if ((wr >> 1) == half) {
                #pragma unroll
                for (int i = 0; i < 4; ++i)
                    #pragma unroll
                    for (int j = 0; j < 4; ++j)
                        #pragma unroll
                        for (int r = 0; r < 4; ++r) {
                            int lrow = (wr & 1) * 64 + i * 16 + quad * 4 + r;  // [0,128)
                            int col = wc * 64 + j * 16 + l16;
                            int ch = col >> 2, off = col & 3;
                            Fs[lrow * 128 + (((ch ^ (lrow & 7)) << 2) | off)] = acc[i][j][r];
                        }
            }
            __syncthreads();
            #pragma unroll
            for (int it = 0; it < 8; ++it) {
                int lrow = it * 16 + (tid >> 5);   // [0,128)
                int ch = tid & 31;
                float4 v = *(const float4*)(Fs + lrow * 128 + ((ch ^ (lrow & 7)) << 2));
                *(float4*)(outf + (bm + half * 128 + lrow) * Ndim + bn + ch * 4) = v;
            }
        }
    }
}

// Fused QKV projection — ONE 768-block launch.
__global__ __launch_bounds__(512) void gemm_qkv3(const ushort_t* __restrict__ A,
                                                 const ushort_t* __restrict__ Wq,
                                                 const ushort_t* __restrict__ Wk,
                                                 const ushort_t* __restrict__ Wv,
                                                 ushort_t* __restrict__ Qo,
                                                 ushort_t* __restrict__ Ko,
                                                 ushort_t* __restrict__ Vto,
                                                 const float* __restrict__ rtab) {
    __shared__ ushort_t smem[4 * PBUF3];   // 96 KB
    const int wsel = blockIdx.y >> 4;      // 0:Q 1:K 2:V
    const int ym   = blockIdx.y & 15;
    const ushort_t* W = (wsel == 0) ? Wq : (wsel == 1) ? Wk : Wv;
    ushort_t* C       = (wsel == 0) ? Qo : (wsel == 1) ? Ko : Vto;
    const int mode = (wsel == 2) ? 2 : 1;
    // same per-group swizzle as a solo launch
    const int wg  = ym * 16 + blockIdx.x;
    const int swz = (wg & 7) * 32 + (wg >> 3);
    const long bm = (long)(swz >> 4) * 256;
    const long bn = (long)(swz & 15) * 128;
    gemm3_body(A, W, C, nullptr, 0, rtab, mode, D_MODEL, bm, bn, smem);
}

// Final output projection (may need fp32 epilogue). hostfl >= 0: host-known
// dtype; -1: read *flag (fallback path).
__global__ __launch_bounds__(512) void gemm_nt3(const ushort_t* __restrict__ A,
                                                const ushort_t* __restrict__ W,
                                                ushort_t* __restrict__ C,
                                                float* __restrict__ outf,
                                                int hostfl,
                                                const int* __restrict__ flag,
                                                const float* __restrict__ rtab,
                                                int mode, int Ndim) {
    __shared__ ushort_t smem[4 * PBUF3];   // 96 KB
    const int wg  = blockIdx.y * 16 + blockIdx.x;
    const int swz = (wg & 7) * 32 + (wg >> 3);
    const long bm = (long)(swz >> 4) * 256;
    const long bn = (long)(swz & 15) * 128;
    // Resolve fl and retire any flag read before the pipeline so the loop's
    // vmcnt counting stays exact.
    int fl = (hostfl >= 0) ? hostfl : *flag;
    asm volatile("" :: "v"(fl));
    asm volatile("s_waitcnt vmcnt(0)" ::: "memory");
    gemm3_body(A, W, C, outf, fl, rtab, mode, Ndim, bm, bn, smem);
}

// ---------------------------------------------------------------------------
// Causal flash attention — R3 structure + R6 CU-draw balancing (84.9 us).
// Blocks round-robin to CUs as {c, c+256, c+512, c+768}; remap g=bx>>5 -> qb
// so each CU draw sums to a constant 62 iters:
//   g in [0,8): 31-g | [8,16): g-8 | [16,24): 39-g | [24,32): g-16
// R4 lesson kept: 1024 blocks, 4/CU, 64 VGPR — do not trade TLP for
// per-block work.
// ---------------------------------------------------------------------------
#define NQT (T_SEQ / 64)
#define C2SM 0.1275174452f   // 128^-0.5 * log2(e)
#define MFIX 96.0f

__global__ __launch_bounds__(256, 4) void attn_kernel(const ushort_t* __restrict__ Q,
                                                      const ushort_t* __restrict__ K,
                                                      const ushort_t* __restrict__ Vt,
                                                      ushort_t* __restrict__ O) {
    __shared__ ushort_t Ks[64 * 128];
    __shared__ ushort_t Vs[128 * 64];
    __shared__ ushort_t Ps[4 * 16 * 64];

    const int tid = threadIdx.x;
    const int lane = tid & 63, w = tid >> 6;
    const int quad = lane >> 4, l16 = lane & 15;
    const int bx = blockIdx.x;
    const int g = bx >> 5;
    int qb;
    if (g < 8)       qb = 31 - g;
    else if (g < 16) qb = g - 8;
    else if (g < 24) qb = 39 - g;
    else             qb = g - 16;
    const int bh = bx & 31;
    const int h = bh & 15, b = bh >> 4;

    const size_t qkbase = ((size_t)(b * T_SEQ)) * D_MODEL + h * HD;
    const size_t vtbase = ((size_t)((b * NH + h) * HD)) * T_SEQ;
    const int ck0 = w * 256 + lane;
    ushort_t* Pw = Ps + w * 1024;

    auto stage_K = [&](int kvb) {
        #pragma unroll
        for (int i = 0; i < 4; ++i) {
            int ck = ck0 + i * 64;
            int r = ck >> 4, gg = (ck & 15) ^ (r & 15);
            g2l16(K + qkbase + (size_t)(kvb * 64 + r) * D_MODEL + gg * 8,
                  (ushort_t*)Ks + (size_t)(w * 256 + i * 64) * 8);
        }
    };
    auto stage_V = [&](int kvb) {
        #pragma unroll
        for (int i = 0; i < 4; ++i) {
            int ck = ck0 + i * 64;
            int r = ck >> 3, gg = (ck & 7) ^ (r & 7);
            g2l16(Vt + vtbase + (size_t)r * T_SEQ + kvb * 64 + gg * 8,
                  (ushort_t*)Vs + (size_t)(w * 256 + i * 64) * 8);
        }
    };

    bf16x8 qf[4];
    {
        const ushort_t* qrow = Q + qkbase + (size_t)(qb * 64 + w * 16 + l16) * D_MODEL;
        #pragma unroll
        for (int ks = 0; ks < 4; ++ks)
            qf[ks] = *(const bf16x8*)(qrow + ks * 32 + quad * 8);
    }

    float l_i[4] = {0.f, 0.f, 0.f, 0.f};   // lane-partial; reduced at end
    f32x4 accO[8];
    for (int i = 0; i < 8; ++i) accO[i] = {0.f, 0.f, 0.f, 0.f};

    stage_K(0);                              // prologue

    for (int kvb = 0; kvb <= qb; ++kvb) {
        __syncthreads();                     // K(kvb) landed; Vs free
        stage_V(kvb);                        // in flight during QK^T+softmax

        f32x4 accS[4];
        for (int i = 0; i < 4; ++i) accS[i] = {0.f, 0.f, 0.f, 0.f};
        __builtin_amdgcn_s_setprio(1);
        #pragma unroll
        for (int ks = 0; ks < 4; ++ks) {
            #pragma unroll
            for (int ct = 0; ct < 4; ++ct) {
                bf16x8 bb = *(const bf16x8*)(Ks + (ct * 16 + l16) * 128 +
                                             (((ks * 4 + quad) ^ l16) * 8));
                accS[ct] = __builtin_amdgcn_mfma_f32_16x16x32_bf16(qf[ks], bb, accS[ct], 0, 0, 0);
            }
        }
        __builtin_amdgcn_s_setprio(0);

        if (kvb == qb) {   // diagonal: causal mask
            int qloc = w * 16 + quad * 4;
            for (int ct = 0; ct < 4; ++ct) {
                int key = ct * 16 + l16;
                for (int r = 0; r < 4; ++r)
                    if (key > qloc + r) accS[ct][r] = -1e30f;
            }
        }

        // p = exp2((s - M) * c); accumulate lane-partial l; store P to LDS
        #pragma unroll
        for (int ct = 0; ct < 4; ++ct) {
            #pragma unroll
            for (int r = 0; r < 4; ++r) {
                float pv = exp2f((accS[ct][r] - MFIX) * C2SM);
                l_i[r] += pv;
                int col = ct * 16 + l16;
                int row = quad * 4 + r;
                Pw[row * 64 + ((((col >> 3) ^ (row & 7)) << 3) | (col & 7))] = f2b(pv);
            }
        }

        __syncthreads();                     // V(kvb) landed; Ks free
        if (kvb < qb) stage_K(kvb + 1);      // in flight during PV

        __builtin_amdgcn_s_setprio(1);
        #pragma unroll
        for (int kk2 = 0; kk2 < 2; ++kk2) {
            bf16x8 a = *(const bf16x8*)(Pw + l16 * 64 + (((kk2 * 4 + quad) ^ (l16 & 7)) << 3));
            #pragma unroll
            for (int ct = 0; ct < 8; ++ct) {
                bf16x8 bb = *(const bf16x8*)(Vs + (ct * 16 + l16) * 64 +
                                             (((kk2 * 4 + quad) ^ (l16 & 7)) * 8));
                accO[ct] = __builtin_amdgcn_mfma_f32_16x16x32_bf16(a, bb, accO[ct], 0, 0, 0);
            }
        }
        __builtin_amdgcn_s_setprio(0);
    }

    // end-of-loop l reduction across the 16 lanes of each quad group
    #pragma unroll
    for (int r = 0; r < 4; ++r) {
        for (int off = 1; off < 16; off <<= 1)
            l_i[r] += __shfl_xor(l_i[r], off);
        l_i[r] = 1.f / l_i[r];
    }

    for (int ct = 0; ct < 8; ++ct)
        for (int r = 0; r < 4; ++r) {
            size_t row = (size_t)(b * T_SEQ + qb * 64 + w * 16 + quad * 4 + r);
            O[row * D_MODEL + h * HD + ct * 16 + l16] = f2b(accO[ct][r] * l_i[r]);
        }
}

// ---------------------------------------------------------------------------
extern "C" void kernel_launch(void* const* d_in, const int* in_sizes, int n_in,
                              void* d_out, int out_size, void* d_ws, size_t ws_size,
                              hipStream_t stream) {
    const size_t TEN = (size_t)M_ROWS * D_MODEL;
    const size_t WEL = (size_t)D_MODEL * D_MODEL;

    char* ws = (char*)d_ws;
    int* flag = (int*)ws;
    ushort_t* xb  = (ushort_t*)(ws + 256);
    ushort_t* Wqb = xb  + TEN;
    ushort_t* Wkb = Wqb + WEL;
    ushort_t* Wvb = Wkb + WEL;
    ushort_t* Wob = Wvb + WEL;
    ushort_t* Qb  = Wob + WEL;
    ushort_t* Kb  = Qb + TEN;
    ushort_t* attn = Kb + TEN;
    ushort_t* Vt  = attn + TEN;
    float* rtab = (float*)(Vt + TEN); // 2048*128 floats = 1 MB

    // Host-side dtype decision from in_sizes[0] (bytes). Fallback to the GPU
    // probe only if the convention is unexpected.
    int hostfl = -1;
    if (in_sizes && n_in > 0) {
        if (in_sizes[0] == (int)(TEN * 4)) hostfl = 1;        // fp32
        else if (in_sizes[0] == (int)(TEN * 2)) hostfl = 0;   // bf16
    }
    if (hostfl < 0)
        detect_dtype<<<1, 256, 0, stream>>>((const ushort_t*)d_in[0], flag);

    convert_rope<<<NCONVB + NROPEB, 256, 0, stream>>>(
        d_in[0], d_in[1], d_in[2], d_in[3], d_in[4], xb, rtab, hostfl, flag);

    // Fused QKV: one 768-block launch.
    gemm_qkv3<<<dim3(16, 48), 512, 0, stream>>>(xb, Wqb, Wkb, Wvb, Qb, Kb, Vt, rtab);

    attn_kernel<<<dim3(NQT * NB * NH), 256, 0, stream>>>(Qb, Kb, Vt, attn);

    gemm_nt3<<<dim3(16, 16), 512, 0, stream>>>(attn, Wob, (ushort_t*)d_out,
                                               (float*)d_out, hostfl, flag, rtab,
                                               0, D_MODEL);
}